// Round 5
// baseline (432.981 us; speedup 1.0000x reference)
//
#include <hip/hip_runtime.h>
#include <stdint.h>

// ---------------------------------------------------------------------------
// kWTA: threshold = K-th largest of N fp32; out[i] = in[i] < thr ? 0 : in[i]
//
// R3 lesson: full-data loops containing an LDS histogram (+ds_atomic) run at
// ~0.7 TB/s (MLP destroyed); plain streaming loops run at 5-6 TB/s. So no
// full-data pass may touch LDS.
// R4 lesson: k_final's scatter-restore MUST run after k_apply's full-output
// stream, or the restored winners get overwritten with zeros.
//
//   K1 k_sample:    1MB sample -> 256-bin hist -> 8-bit cutoff b8
//   K2 k_gather:    stream 128MB, push (key,idx) of tail (~2.3%) into 256
//                   region-partitioned buffers (no LDS, distributed atomics)
//   K3 k_hist_cand: 4096-bin hist over candidates only (~3MB); last block
//                   selects threshold bin + rank (sets FB flag on miss)
//   K4 k_fb:        flag-gated full-hist fallback (pathological data only)
//   K5 k_apply:     pure stream: bin>sel -> copy, else 0 (256MB)
//   K6 k_extract:   pull bin==sel pairs (~2K) from candidates (or input if FB)
//   K7 k_final:     exact 20-bit radix select + scatter-restore winners
// ---------------------------------------------------------------------------

#define HIST_BINS 4096
#define SAMPLE_BLOCKS 64
#define SAMPLE_F4_PER_BLOCK 1024
#define SAMPLE_M (SAMPLE_BLOCKS * SAMPLE_F4_PER_BLOCK * 4)

#define NREG 256          // gather regions

// ws word offsets
#define CH_OFF        0      // candidate hist, 4096
#define FBH_OFF       4096   // fallback hist, 4096
#define SAMP_HIST_OFF 8192   // 256
#define CNT_OFF       8448   // 256 region counters
#define DONE_SAMP     8704
#define DONE_CH       8705
#define DONE_FB       8706
#define FB_FLAG       8707
#define B8_OFF        8708
#define CTRL_OFF      8712   // [0]=extract ctr [1]=sel bin [2]=want [3]=thr
#define ZERO_WORDS    8720
#define CAND_OFF      8720

__device__ __forceinline__ uint32_t f2key(float x) {
  uint32_t u = __float_as_uint(x);
  return (u & 0x80000000u) ? ~u : (u | 0x80000000u);
}
__device__ __forceinline__ float key2f(uint32_t k) {
  uint32_t u = (k & 0x80000000u) ? (k & 0x7fffffffu) : ~k;
  return __uint_as_float(u);
}

__device__ __forceinline__ void histAdd8(uint32_t* lh, uint32_t bin) {
  unsigned long long peers = __ballot(1);
#pragma unroll
  for (int b = 0; b < 8; b++) {
    unsigned long long vote = __ballot((bin >> b) & 1u);
    peers &= ((bin >> b) & 1u) ? vote : ~vote;
  }
  unsigned lane = threadIdx.x & 63u;
  if (lane == (unsigned)(__ffsll((long long)peers) - 1))
    atomicAdd(&lh[bin], (uint32_t)__popcll(peers));
}

// suffix-scan a 4096-bin hist from the top; ctrl[1]=bin, ctrl[2]=rank.
__device__ void select4096(const uint32_t* __restrict__ gh, uint32_t K,
                           uint32_t* __restrict__ ctrl,
                           uint32_t* __restrict__ fbflag,  // null = clamp mode
                           uint32_t* lh, uint32_t* chunk) {
  int t = threadIdx.x;
  for (int i = t; i < HIST_BINS; i += 256) lh[i] = gh[i];
  __syncthreads();
  uint32_t s = 0;
#pragma unroll
  for (int i = 0; i < 16; i++) s += lh[t * 16 + i];
  chunk[t] = s;
  __syncthreads();
  if (t == 0) {
    uint32_t above = 0;
    int sel = -1;
    for (int c = 255; c >= 0; c--) {
      if (above + chunk[c] >= K) { sel = c; break; }
      above += chunk[c];
    }
    if (sel < 0) {
      if (fbflag) { *fbflag = 1u; }
      else { ctrl[1] = 0u; ctrl[2] = 0xFFFFFFFFu; }  // keep everything
    } else {
      int bsel = sel * 16;
      for (int b = sel * 16 + 15; b >= sel * 16; b--) {
        uint32_t c = lh[b];
        if (above + c >= K) { bsel = b; break; }
        above += c;
      }
      ctrl[1] = (uint32_t)bsel;
      ctrl[2] = K - above;
    }
  }
}

__global__ void k_sample(const float4* __restrict__ in, int n4,
                         const int* __restrict__ kptr, uint32_t n,
                         uint32_t* __restrict__ ws) {
  __shared__ uint32_t lh[256];
  __shared__ uint32_t s_last;
  int t = threadIdx.x;
  if (t < 256) lh[t] = 0;
  __syncthreads();
  if (n4 >= SAMPLE_F4_PER_BLOCK) {
    int chunkf4 = n4 / SAMPLE_BLOCKS;
    int base = blockIdx.x * chunkf4;
    if (base + SAMPLE_F4_PER_BLOCK > n4) base = n4 - SAMPLE_F4_PER_BLOCK;
#pragma unroll
    for (int j = 0; j < 4; j++) {
      float4 v = in[base + t + j * 256];
      histAdd8(lh, f2key(v.x) >> 24);
      histAdd8(lh, f2key(v.y) >> 24);
      histAdd8(lh, f2key(v.z) >> 24);
      histAdd8(lh, f2key(v.w) >> 24);
    }
  }
  __syncthreads();
  if (t < 256) {
    uint32_t c = lh[t];
    if (c) atomicAdd(&ws[SAMP_HIST_OFF + t], c);
  }
  __threadfence();
  if (t == 0) s_last = atomicAdd(&ws[DONE_SAMP], 1u);
  __syncthreads();
  if (s_last == SAMPLE_BLOCKS - 1) {
    __threadfence();
    if (t < 256) lh[t] = ws[SAMP_HIST_OFF + t];
    __syncthreads();
    if (t == 0) {
      int kv = kptr[0];
      uint32_t K = (kv < 1) ? 1u : (uint32_t)kv;
      uint64_t tgt64 = ((uint64_t)K * SAMPLE_M / (n ? n : 1u)) * 2u + 4096u;
      uint32_t target = (tgt64 > SAMPLE_M) ? (uint32_t)SAMPLE_M : (uint32_t)tgt64;
      if (target < 4096u) target = 4096u;
      uint32_t sum = 0; uint32_t b8 = 0;
      for (int b = 255; b >= 0; b--) {
        sum += lh[b];
        if (sum >= target) { b8 = (uint32_t)b; break; }
      }
      ws[B8_OFF] = b8;  // unreachable target -> b8=0 -> tail = everything
    }
  }
}

// Pure streaming gather: no LDS. (key,idx) pairs go to region blockIdx&255.
__global__ void k_gather(const float4* __restrict__ in, int n4, int ntail,
                         const float* __restrict__ in_s,
                         uint32_t* __restrict__ ws, uint32_t regSize) {
  uint32_t b8 = ws[B8_OFF];
  uint32_t* cnt = ws + CNT_OFF;
  uint32_t* keysT = ws + CAND_OFF;
  uint32_t* idxT = keysT + (size_t)NREG * regSize;
  int r = blockIdx.x & (NREG - 1);
  uint32_t rbase = (uint32_t)r * regSize;
  int stride = gridDim.x * blockDim.x;
  for (int i = blockIdx.x * blockDim.x + threadIdx.x; i < n4; i += stride) {
    float4 v = in[i];
    uint32_t k0 = f2key(v.x), k1 = f2key(v.y), k2 = f2key(v.z), k3 = f2key(v.w);
    uint32_t lk[4], li[4];
    int nq = 0;
    uint32_t base = 4u * (uint32_t)i;
    if ((k0 >> 24) >= b8) { lk[nq] = k0; li[nq] = base + 0u; nq++; }
    if ((k1 >> 24) >= b8) { lk[nq] = k1; li[nq] = base + 1u; nq++; }
    if ((k2 >> 24) >= b8) { lk[nq] = k2; li[nq] = base + 2u; nq++; }
    if ((k3 >> 24) >= b8) { lk[nq] = k3; li[nq] = base + 3u; nq++; }
    if (nq) {
      uint32_t p = atomicAdd(&cnt[r], (uint32_t)nq);
#pragma unroll
      for (int j = 0; j < 4; j++)
        if (j < nq) {
          uint32_t q = p + (uint32_t)j;
          if (q < regSize) { keysT[rbase + q] = lk[j]; idxT[rbase + q] = li[j]; }
        }
    }
  }
  if (blockIdx.x == 0 && (int)threadIdx.x < ntail) {
    int jdx = n4 * 4 + threadIdx.x;
    uint32_t kk = f2key(in_s[jdx]);
    if ((kk >> 24) >= b8) {
      uint32_t p = atomicAdd(&cnt[0], 1u);
      if (p < regSize) { keysT[p] = kk; idxT[p] = (uint32_t)jdx; }
    }
  }
}

// Histogram the candidate list only (~3MB); last block selects bin+rank.
__global__ void k_hist_cand(uint32_t* __restrict__ ws, uint32_t regSize,
                            const int* __restrict__ kptr, uint32_t n) {
  __shared__ uint32_t lh[HIST_BINS];
  __shared__ uint32_t chunk[256];
  __shared__ uint32_t s_last;
  int t = threadIdx.x;
  int b = blockIdx.x;  // one block per region; grid == NREG
  for (int i = t; i < HIST_BINS; i += blockDim.x) lh[i] = 0;
  __syncthreads();
  uint32_t c = ws[CNT_OFF + b];
  uint32_t used = (c > regSize) ? regSize : c;
  if (c > regSize && t == 0) ws[FB_FLAG] = 1u;  // lost candidates -> fallback
  const uint32_t* keysT = ws + CAND_OFF;
  uint32_t rbase = (uint32_t)b * regSize;
  for (uint32_t j = t; j < used; j += blockDim.x)
    atomicAdd(&lh[keysT[rbase + j] >> 20], 1u);
  __syncthreads();
  for (int i = t; i < HIST_BINS; i += blockDim.x) {
    uint32_t cc = lh[i];
    if (cc) atomicAdd(&ws[CH_OFF + i], cc);
  }
  __threadfence();
  if (t == 0) s_last = atomicAdd(&ws[DONE_CH], 1u);
  __syncthreads();
  if (s_last == (uint32_t)(NREG - 1)) {
    __threadfence();
    if (ws[FB_FLAG] == 0u) {
      int kv = kptr[0];
      uint32_t K = (kv < 1) ? 1u : (uint32_t)kv;
      if (K > n) K = n;
      select4096(ws + CH_OFF, K, ws + CTRL_OFF, ws + FB_FLAG, lh, chunk);
    }
  }
}

// Pathological fallback: full histogram of everything (slow, flag-gated).
__global__ void k_fb(const float4* __restrict__ in, int n4, int ntail,
                     const float* __restrict__ in_s,
                     const int* __restrict__ kptr,
                     uint32_t* __restrict__ ws, int nblocks, uint32_t n) {
  __shared__ uint32_t lh[HIST_BINS];
  __shared__ uint32_t chunk[256];
  __shared__ uint32_t s_flag, s_last;
  int t = threadIdx.x;
  if (t == 0) s_flag = ws[FB_FLAG];
  __syncthreads();
  if (!s_flag) return;
  for (int i = t; i < HIST_BINS; i += blockDim.x) lh[i] = 0;
  __syncthreads();
  int stride = gridDim.x * blockDim.x;
  for (int i = blockIdx.x * blockDim.x + t; i < n4; i += stride) {
    float4 v = in[i];
    atomicAdd(&lh[f2key(v.x) >> 20], 1u);
    atomicAdd(&lh[f2key(v.y) >> 20], 1u);
    atomicAdd(&lh[f2key(v.z) >> 20], 1u);
    atomicAdd(&lh[f2key(v.w) >> 20], 1u);
  }
  if (blockIdx.x == 0 && t < ntail)
    atomicAdd(&lh[f2key(in_s[n4 * 4 + t]) >> 20], 1u);
  __syncthreads();
  for (int i = t; i < HIST_BINS; i += blockDim.x) {
    uint32_t c = lh[i];
    if (c) atomicAdd(&ws[FBH_OFF + i], c);
  }
  __threadfence();
  if (t == 0) s_last = atomicAdd(&ws[DONE_FB], 1u);
  __syncthreads();
  if (s_last == (uint32_t)(nblocks - 1)) {
    __threadfence();
    int kv = kptr[0];
    uint32_t K = (kv < 1) ? 1u : (uint32_t)kv;
    if (K > n) K = n;
    select4096(ws + FBH_OFF, K, ws + CTRL_OFF, nullptr, lh, chunk);
  }
}

// Pure streaming apply: bin>sel -> copy, else zero (k_final restores sel-bin
// winners AFTERWARDS — order matters, see R4 lesson).
__global__ void k_apply(const float4* __restrict__ in, float4* __restrict__ out,
                        int n4, int ntail,
                        const float* __restrict__ in_s, float* __restrict__ out_s,
                        const uint32_t* __restrict__ ctrl) {
  uint32_t sel = ctrl[1];
  int stride = gridDim.x * blockDim.x;
  for (int i = blockIdx.x * blockDim.x + threadIdx.x; i < n4; i += stride) {
    float4 v = in[i];
    float4 r;
    r.x = ((f2key(v.x) >> 20) > sel) ? v.x : 0.0f;
    r.y = ((f2key(v.y) >> 20) > sel) ? v.y : 0.0f;
    r.z = ((f2key(v.z) >> 20) > sel) ? v.z : 0.0f;
    r.w = ((f2key(v.w) >> 20) > sel) ? v.w : 0.0f;
    __builtin_nontemporal_store(r.x, &((float*)&out[i])[0]);
    __builtin_nontemporal_store(r.y, &((float*)&out[i])[1]);
    __builtin_nontemporal_store(r.z, &((float*)&out[i])[2]);
    __builtin_nontemporal_store(r.w, &((float*)&out[i])[3]);
  }
  if (blockIdx.x == 0 && (int)threadIdx.x < ntail) {
    int j = n4 * 4 + threadIdx.x;
    float x = in_s[j];
    out_s[j] = ((f2key(x) >> 20) > sel) ? x : 0.0f;
  }
}

// Pull bin==sel pairs into the extract buffer (from regions, or input if FB).
__global__ void k_extract(const float4* __restrict__ in, int n4, int ntail,
                          const float* __restrict__ in_s,
                          uint32_t* __restrict__ ws, uint32_t regSize,
                          uint32_t* __restrict__ keysE,
                          uint32_t* __restrict__ idxE, uint32_t capE) {
  uint32_t* ctrl = ws + CTRL_OFF;
  uint32_t sel = ctrl[1];
  uint32_t fb = ws[FB_FLAG];
  int t = threadIdx.x;
  if (!fb) {
    const uint32_t* keysT = ws + CAND_OFF;
    const uint32_t* idxT = keysT + (size_t)NREG * regSize;
    for (int r = blockIdx.x; r < NREG; r += gridDim.x) {
      uint32_t c = ws[CNT_OFF + r];
      uint32_t used = (c > regSize) ? regSize : c;
      uint32_t rbase = (uint32_t)r * regSize;
      for (uint32_t j = t; j < used; j += blockDim.x) {
        uint32_t kk = keysT[rbase + j];
        if ((kk >> 20) == sel) {
          uint32_t p = atomicAdd(&ctrl[0], 1u);
          if (p < capE) { keysE[p] = kk; idxE[p] = idxT[rbase + j]; }
        }
      }
    }
  } else {
    int stride = gridDim.x * blockDim.x;
    for (int i = blockIdx.x * blockDim.x + t; i < n4; i += stride) {
      float4 v = in[i];
      uint32_t kk[4] = {f2key(v.x), f2key(v.y), f2key(v.z), f2key(v.w)};
#pragma unroll
      for (int j = 0; j < 4; j++)
        if ((kk[j] >> 20) == sel) {
          uint32_t p = atomicAdd(&ctrl[0], 1u);
          if (p < capE) { keysE[p] = kk[j]; idxE[p] = 4u * (uint32_t)i + (uint32_t)j; }
        }
    }
    if (blockIdx.x == 0 && t < ntail) {
      int jdx = n4 * 4 + t;
      uint32_t kk = f2key(in_s[jdx]);
      if ((kk >> 20) == sel) {
        uint32_t p = atomicAdd(&ctrl[0], 1u);
        if (p < capE) { keysE[p] = kk; idxE[p] = (uint32_t)jdx; }
      }
    }
  }
}

// Exact 20-bit radix select over extracted pairs; scatter-restore winners.
__global__ void __launch_bounds__(1024) k_final(uint32_t* __restrict__ ctrl,
                                                const uint32_t* __restrict__ keysE,
                                                const uint32_t* __restrict__ idxE,
                                                uint32_t capE,
                                                const float* __restrict__ in,
                                                float* __restrict__ out,
                                                uint32_t n) {
  __shared__ uint32_t sh[8192];
  __shared__ uint32_t red[16];
  __shared__ uint32_t s_p, s_want;
  int t = threadIdx.x;
  uint32_t n2 = ctrl[0];
  bool of = (n2 > capE);       // extract overflow: correct-but-slow input path
  uint32_t m = of ? n : n2;    // elements to scan per pass
  bool useLds = (!of && n2 <= 8192);
  if (useLds) for (uint32_t i = t; i < n2; i += blockDim.x) sh[i] = keysE[i];
  if (t == 0) { s_p = ctrl[1] << 20; s_want = ctrl[2]; }
  __syncthreads();
  uint32_t p = s_p, want = s_want;
  uint32_t selbin = ctrl[1];
  for (int bit = 19; bit >= 0; bit--) {
    uint32_t test = p | (1u << bit);
    uint32_t hi = test >> bit;
    uint32_t cnt = 0;
    for (uint32_t i = t; i < m; i += blockDim.x) {
      uint32_t kk;
      if (of) { kk = f2key(in[i]); if ((kk >> 20) != selbin) continue; }
      else kk = useLds ? sh[i] : keysE[i];
      cnt += ((kk >> bit) == hi) ? 1u : 0u;
    }
    for (int off = 32; off; off >>= 1) cnt += __shfl_down((int)cnt, off);
    int wave = t >> 6, lane = t & 63;
    if (lane == 0) red[wave] = cnt;
    __syncthreads();
    if (t == 0) {
      uint32_t tot = 0;
      for (int w = 0; w < 16; w++) tot += red[w];
      if (tot >= want) p = test; else want -= tot;
      s_p = p; s_want = want;
    }
    __syncthreads();
    p = s_p; want = s_want;
  }
  if (t == 0) ctrl[3] = __float_as_uint(key2f(p));
  if (!of) {
    for (uint32_t i = t; i < n2; i += blockDim.x) {
      uint32_t kk = useLds ? sh[i] : keysE[i];
      if (kk >= p) out[idxE[i]] = key2f(kk);
    }
  } else {
    for (uint32_t i = t; i < n; i += blockDim.x) {
      uint32_t kk = f2key(in[i]);
      if ((kk >> 20) == selbin && kk >= p) out[i] = key2f(kk);
    }
  }
}

extern "C" void kernel_launch(void* const* d_in, const int* in_sizes, int n_in,
                              void* d_out, int out_size, void* d_ws, size_t ws_size,
                              hipStream_t stream) {
  const float* in = (const float*)d_in[0];
  const int* kptr = (const int*)d_in[1];
  float* out = (float*)d_out;
  int n = in_sizes[0];
  int n4 = n >> 2;
  int ntail = n & 3;

  uint32_t* ws = (uint32_t*)d_ws;
  uint32_t* ctrl = ws + CTRL_OFF;
  size_t ws_words = ws_size / 4;

  // partition candidate space: total pairs P; 1/8 to extract, rest to regions
  size_t avail = (ws_words > CAND_OFF) ? (ws_words - CAND_OFF) : 0;
  size_t P = avail / 2;                       // (key,idx) costs 2 words
  uint32_t capE = (uint32_t)(P / 8);
  uint32_t regSize = (uint32_t)((P - capE) / NREG);
  uint32_t* keysE = ws + CAND_OFF + (size_t)NREG * regSize * 2;
  uint32_t* idxE = keysE + capE;

  hipMemsetAsync(d_ws, 0, ZERO_WORDS * sizeof(uint32_t), stream);
  k_sample<<<SAMPLE_BLOCKS, 256, 0, stream>>>((const float4*)in, n4, kptr,
                                              (uint32_t)n, ws);
  k_gather<<<4096, 256, 0, stream>>>((const float4*)in, n4, ntail, in, ws, regSize);
  k_hist_cand<<<NREG, 256, 0, stream>>>(ws, regSize, kptr, (uint32_t)n);
  k_fb<<<1024, 256, 0, stream>>>((const float4*)in, n4, ntail, in, kptr,
                                 ws, 1024, (uint32_t)n);
  k_apply<<<4096, 256, 0, stream>>>((const float4*)in, (float4*)out, n4, ntail,
                                    in, out, ctrl);
  k_extract<<<512, 256, 0, stream>>>((const float4*)in, n4, ntail, in, ws,
                                     regSize, keysE, idxE, capE);
  k_final<<<1, 1024, 0, stream>>>(ctrl, keysE, idxE, capE, in, out, (uint32_t)n);
}

// Round 6
// 364.401 us; speedup vs baseline: 1.1882x; 1.1882x over previous
//
#include <hip/hip_runtime.h>
#include <stdint.h>
#include <math.h>

// ---------------------------------------------------------------------------
// kWTA: threshold = K-th largest of N fp32; out[i] = in[i] < thr ? 0 : in[i]
//
// R3/R5 lesson: any full-data loop whose wave executes an atomic ~every
// iteration (LDS or global) runs at ~0.8 TB/s; pure streams run 5-6 TB/s.
// R5 lesson: 8-bit key buckets span 2 octaves -> tail estimate off by 100x.
// R4 lesson: the fixup kernel must be the LAST writer of out.
//
//   K1 k_sample:       1M-elem sample, 12-bit hist -> cut (LCB(count)>=K)
//   K2 k_apply_gather: THE single full pass: out = key>=cut ? v : 0 (NT
//                      stores) + ballot-compacted (key,idx) into per-wave
//                      regions. ZERO atomics in the loop.
//   K3 k_compact:      regions -> contiguous list (1 atomic/region);
//                      sets FB if total<K or overflow
//   K4 k_fb_hist:      [gated] full 12-bit hist + select bin/rank
//   K5 k_fb_ag:        [gated] re-apply: >sel keep, ==sel 0+record, <sel 0
//   K6 k_final:        exact radix select; happy: zero losers; fb: restore
//                      winners (slow exact path if fb buffer overflowed)
// ---------------------------------------------------------------------------

#define NW 4096          // apply_gather waves (1024 blocks x 4 waves)
#define FB_CAP 16384
#define CMP_CAP 32768

// ws word offsets
#define SH_OFF   0       // sample hist 4096
#define WCNT_OFF 4096    // per-wave candidate counts, NW
#define FBH_OFF  8192    // fallback hist 4096
#define CTRL     12288   // 16 control words
#define FBPK_OFF 12304
#define FBPI_OFF (12304 + FB_CAP)
#define CMPK_OFF 45072
#define CMPI_OFF (45072 + CMP_CAP)
#define REG_OFF  110608
#define ZERO_WORDS 12304

// ctrl indices
#define C_TOT   0   // compacted candidate count
#define C_SEL   1   // fb: selected 12-bit bin
#define C_WANT  2   // fb: rank within bin
#define C_THR   3   // threshold key bits (debug)
#define C_FBN   4   // fb pair count
#define C_DSAMP 5
#define C_DCOMP 6
#define C_FLAG  7   // fallback flag
#define C_CUT   8   // 12-bit cut bin
#define C_DFBH  9

__device__ __forceinline__ uint32_t f2key(float x) {
  uint32_t u = __float_as_uint(x);
  return (u & 0x80000000u) ? ~u : (u | 0x80000000u);  // larger key <=> larger float
}
__device__ __forceinline__ float key2f(uint32_t k) {
  uint32_t u = (k & 0x80000000u) ? (k & 0x7fffffffu) : ~k;
  return __uint_as_float(u);
}

// suffix-scan a 4096-bin hist from the top; ctrl[C_SEL]=bin, ctrl[C_WANT]=rank.
__device__ void select4096(const uint32_t* __restrict__ gh, uint32_t K,
                           uint32_t* __restrict__ ctrl,
                           uint32_t* lh, uint32_t* chunk) {
  int t = threadIdx.x;
  for (int i = t; i < 4096; i += 256) lh[i] = gh[i];
  __syncthreads();
  uint32_t s = 0;
#pragma unroll
  for (int i = 0; i < 16; i++) s += lh[t * 16 + i];
  chunk[t] = s;
  __syncthreads();
  if (t == 0) {
    uint32_t above = 0;
    int sel = -1;
    for (int c = 255; c >= 0; c--) {
      if (above + chunk[c] >= K) { sel = c; break; }
      above += chunk[c];
    }
    if (sel < 0) { ctrl[C_SEL] = 0u; ctrl[C_WANT] = 0xFFFFFFFFu; }  // keep all
    else {
      int bsel = sel * 16;
      for (int b = sel * 16 + 15; b >= sel * 16; b--) {
        uint32_t c = lh[b];
        if (above + c >= K) { bsel = b; break; }
        above += c;
      }
      ctrl[C_SEL] = (uint32_t)bsel;
      ctrl[C_WANT] = K - above;  // 1-based rank within bin, from the top
    }
  }
}

// 256 blocks x 4096 elements = 1M sample; 12-bit hist; last block picks cut.
__global__ void k_sample(const float4* __restrict__ in, int n4,
                         const int* __restrict__ kptr, uint32_t n,
                         uint32_t* __restrict__ ws) {
  __shared__ uint32_t lh[4096];
  __shared__ uint32_t chunk[256];
  __shared__ uint32_t s_last;
  int t = threadIdx.x;
  for (int i = t; i < 4096; i += 256) lh[i] = 0;
  __syncthreads();
  int chunkf4 = n4 / 256;
  if (chunkf4 >= 1024) {
    int base = blockIdx.x * chunkf4;
#pragma unroll
    for (int j = 0; j < 4; j++) {
      float4 v = in[base + t + j * 256];
      atomicAdd(&lh[f2key(v.x) >> 20], 1u);
      atomicAdd(&lh[f2key(v.y) >> 20], 1u);
      atomicAdd(&lh[f2key(v.z) >> 20], 1u);
      atomicAdd(&lh[f2key(v.w) >> 20], 1u);
    }
  }
  __syncthreads();
  for (int i = t; i < 4096; i += 256) {
    uint32_t c = lh[i];
    if (c) atomicAdd(&ws[SH_OFF + i], c);
  }
  __threadfence();
  if (t == 0) s_last = atomicAdd(&ws[CTRL + C_DSAMP], 1u);
  __syncthreads();
  if (s_last == gridDim.x - 1) {
    __threadfence();
    for (int i = t; i < 4096; i += 256) lh[i] = ws[SH_OFF + i];
    __syncthreads();
    uint32_t s = 0;
#pragma unroll
    for (int i = 0; i < 16; i++) s += lh[t * 16 + i];
    chunk[t] = s;
    __syncthreads();
    if (t == 0) {
      int kv = kptr[0];
      uint32_t K = (kv < 1) ? 1u : (uint32_t)kv;
      if (K > n) K = n;
      // smallest sample-suffix s* with N/M*(s - 8*sqrt(s) - 8) >= K
      double A = (double)K * 1048576.0 / (double)(n ? n : 1u);
      double x = 4.0 + sqrt(A + 24.0);
      uint32_t smin = (uint32_t)(x * x) + 1u;
      if (smin < 64u) smin = 64u;
      uint32_t acc = 0, cut = 0;
      for (int c = 255; c >= 0; c--) {
        if (acc + chunk[c] >= smin) {
          for (int b = c * 16 + 15; b >= c * 16; b--) {
            acc += lh[b];
            if (acc >= smin) { cut = (uint32_t)b; break; }
          }
          break;
        }
        acc += chunk[c];
      }
      ws[CTRL + C_CUT] = cut;  // cut=0 if never reached -> all cands -> FB
    }
  }
}

// The single full pass. No atomics in the loop: ballot-compacted appends
// into per-wave private regions; per-wave count via plain store at the end.
__global__ void k_apply_gather(const float4* __restrict__ in,
                               float4* __restrict__ out, int n4, int ntail,
                               const float* __restrict__ in_s,
                               float* __restrict__ out_s,
                               uint32_t* __restrict__ ws,
                               uint32_t* __restrict__ keysR,
                               uint32_t* __restrict__ idxR, uint32_t cap) {
  const uint32_t cutK = ws[CTRL + C_CUT] << 20;
  int lane = threadIdx.x & 63;
  uint64_t lt = (1ULL << lane) - 1ULL;
  int wave = (int)((blockIdx.x * blockDim.x + threadIdx.x) >> 6);
  uint32_t rbase = (uint32_t)wave * cap;
  uint32_t wcount = 0;
  int stride = gridDim.x * blockDim.x;
  for (int i = blockIdx.x * blockDim.x + threadIdx.x; i < n4; i += stride) {
    float4 v = in[i];
    uint32_t k0 = f2key(v.x), k1 = f2key(v.y), k2 = f2key(v.z), k3 = f2key(v.w);
    bool q0 = k0 >= cutK, q1 = k1 >= cutK, q2 = k2 >= cutK, q3 = k3 >= cutK;
    float4 r;
    r.x = q0 ? v.x : 0.0f;
    r.y = q1 ? v.y : 0.0f;
    r.z = q2 ? v.z : 0.0f;
    r.w = q3 ? v.w : 0.0f;
    __builtin_nontemporal_store(r.x, &((float*)&out[i])[0]);
    __builtin_nontemporal_store(r.y, &((float*)&out[i])[1]);
    __builtin_nontemporal_store(r.z, &((float*)&out[i])[2]);
    __builtin_nontemporal_store(r.w, &((float*)&out[i])[3]);
    if (__ballot(q0 | q1 | q2 | q3)) {  // rare (~6% of wave-iters)
      uint32_t base = 4u * (uint32_t)i;
      uint64_t m0 = __ballot(q0);
      if (q0) { uint32_t o = wcount + (uint32_t)__popcll(m0 & lt); if (o < cap) { keysR[rbase + o] = k0; idxR[rbase + o] = base; } }
      wcount += (uint32_t)__popcll(m0);
      uint64_t m1 = __ballot(q1);
      if (q1) { uint32_t o = wcount + (uint32_t)__popcll(m1 & lt); if (o < cap) { keysR[rbase + o] = k1; idxR[rbase + o] = base + 1u; } }
      wcount += (uint32_t)__popcll(m1);
      uint64_t m2 = __ballot(q2);
      if (q2) { uint32_t o = wcount + (uint32_t)__popcll(m2 & lt); if (o < cap) { keysR[rbase + o] = k2; idxR[rbase + o] = base + 2u; } }
      wcount += (uint32_t)__popcll(m2);
      uint64_t m3 = __ballot(q3);
      if (q3) { uint32_t o = wcount + (uint32_t)__popcll(m3 & lt); if (o < cap) { keysR[rbase + o] = k3; idxR[rbase + o] = base + 3u; } }
      wcount += (uint32_t)__popcll(m3);
    }
  }
  if (blockIdx.x == 0 && (threadIdx.x >> 6) == 0) {  // scalar tail, wave 0
    int j = n4 * 4 + lane;
    bool q = false;
    uint32_t kk = 0;
    if (lane < ntail) {
      float x = in_s[j];
      kk = f2key(x);
      q = kk >= cutK;
      out_s[j] = q ? x : 0.0f;
    }
    uint64_t mq = __ballot(q);
    if (q) { uint32_t o = wcount + (uint32_t)__popcll(mq & lt); if (o < cap) { keysR[rbase + o] = kk; idxR[rbase + o] = (uint32_t)j; } }
    wcount += (uint32_t)__popcll(mq);
  }
  if (lane == 0) {
    ws[WCNT_OFF + wave] = wcount;
    if (wcount > cap) ws[CTRL + C_FLAG] = 1u;  // lost records -> fallback
  }
}

// Regions -> contiguous list; one atomic per region. Last block: FB checks.
__global__ void k_compact(uint32_t* __restrict__ ws,
                          const uint32_t* __restrict__ keysR,
                          const uint32_t* __restrict__ idxR,
                          uint32_t cap, uint32_t cmpcap,
                          const int* __restrict__ kptr, uint32_t n) {
  __shared__ uint32_t s_last;
  int t = threadIdx.x;
  int lane = t & 63;
  int gw = (int)((blockIdx.x * blockDim.x + t) >> 6);  // 0..255
  for (int r = gw * 16; r < gw * 16 + 16; r++) {
    uint32_t c = ws[WCNT_OFF + r];
    if (c > cap) c = cap;
    if (c) {
      uint32_t p = 0;
      if (lane == 0) p = atomicAdd(&ws[CTRL + C_TOT], c);
      p = (uint32_t)__shfl((int)p, 0);
      for (uint32_t j = lane; j < c; j += 64) {
        uint32_t d = p + j;
        if (d < cmpcap) {
          ws[CMPK_OFF + d] = keysR[(size_t)r * cap + j];
          ws[CMPI_OFF + d] = idxR[(size_t)r * cap + j];
        } else ws[CTRL + C_FLAG] = 1u;
      }
    }
  }
  __threadfence();
  __syncthreads();
  if (t == 0) s_last = atomicAdd(&ws[CTRL + C_DCOMP], 1u);
  __syncthreads();
  if (s_last == gridDim.x - 1 && t == 0) {
    __threadfence();
    int kv = kptr[0];
    uint32_t K = (kv < 1) ? 1u : (uint32_t)kv;
    if (K > n) K = n;
    uint32_t tot = ws[CTRL + C_TOT];
    if (tot < K || tot > cmpcap) ws[CTRL + C_FLAG] = 1u;
  }
}

// [gated] full 12-bit hist (slow, correctness-only) + select bin/rank.
__global__ void k_fb_hist(const float4* __restrict__ in, int n4, int ntail,
                          const float* __restrict__ in_s,
                          const int* __restrict__ kptr,
                          uint32_t* __restrict__ ws, uint32_t n) {
  __shared__ uint32_t lh[4096];
  __shared__ uint32_t chunk[256];
  __shared__ uint32_t s_flag, s_last;
  int t = threadIdx.x;
  if (t == 0) s_flag = ws[CTRL + C_FLAG];
  __syncthreads();
  if (!s_flag) return;
  for (int i = t; i < 4096; i += 256) lh[i] = 0;
  __syncthreads();
  int stride = gridDim.x * blockDim.x;
  for (int i = blockIdx.x * blockDim.x + t; i < n4; i += stride) {
    float4 v = in[i];
    atomicAdd(&lh[f2key(v.x) >> 20], 1u);
    atomicAdd(&lh[f2key(v.y) >> 20], 1u);
    atomicAdd(&lh[f2key(v.z) >> 20], 1u);
    atomicAdd(&lh[f2key(v.w) >> 20], 1u);
  }
  if (blockIdx.x == 0 && t < ntail)
    atomicAdd(&lh[f2key(in_s[n4 * 4 + t]) >> 20], 1u);
  __syncthreads();
  for (int i = t; i < 4096; i += 256) {
    uint32_t c = lh[i];
    if (c) atomicAdd(&ws[FBH_OFF + i], c);
  }
  __threadfence();
  if (t == 0) s_last = atomicAdd(&ws[CTRL + C_DFBH], 1u);
  __syncthreads();
  if (s_last == gridDim.x - 1) {
    __threadfence();
    int kv = kptr[0];
    uint32_t K = (kv < 1) ? 1u : (uint32_t)kv;
    if (K > n) K = n;
    select4096(ws + FBH_OFF, K, ws + CTRL, lh, chunk);
  }
}

// [gated] exact re-apply: >sel keep, ==sel provisional 0 + record, <sel 0.
__global__ void k_fb_ag(const float4* __restrict__ in, float4* __restrict__ out,
                        int n4, int ntail,
                        const float* __restrict__ in_s, float* __restrict__ out_s,
                        uint32_t* __restrict__ ws, uint32_t fbcap) {
  __shared__ uint32_t s_flag;
  if (threadIdx.x == 0) s_flag = ws[CTRL + C_FLAG];
  __syncthreads();
  if (!s_flag) return;
  uint32_t sel = ws[CTRL + C_SEL];
  uint32_t* keysF = ws + FBPK_OFF;
  uint32_t* idxF = ws + FBPI_OFF;
  int stride = gridDim.x * blockDim.x;
  for (int i = blockIdx.x * blockDim.x + threadIdx.x; i < n4; i += stride) {
    float4 v = in[i];
    uint32_t k0 = f2key(v.x), k1 = f2key(v.y), k2 = f2key(v.z), k3 = f2key(v.w);
    uint32_t b0 = k0 >> 20, b1 = k1 >> 20, b2 = k2 >> 20, b3 = k3 >> 20;
    float4 r;
    r.x = (b0 > sel) ? v.x : 0.0f;
    r.y = (b1 > sel) ? v.y : 0.0f;
    r.z = (b2 > sel) ? v.z : 0.0f;
    r.w = (b3 > sel) ? v.w : 0.0f;
    out[i] = r;
    uint32_t base = 4u * (uint32_t)i;
    if (b0 == sel) { uint32_t p = atomicAdd(&ws[CTRL + C_FBN], 1u); if (p < fbcap) { keysF[p] = k0; idxF[p] = base; } }
    if (b1 == sel) { uint32_t p = atomicAdd(&ws[CTRL + C_FBN], 1u); if (p < fbcap) { keysF[p] = k1; idxF[p] = base + 1u; } }
    if (b2 == sel) { uint32_t p = atomicAdd(&ws[CTRL + C_FBN], 1u); if (p < fbcap) { keysF[p] = k2; idxF[p] = base + 2u; } }
    if (b3 == sel) { uint32_t p = atomicAdd(&ws[CTRL + C_FBN], 1u); if (p < fbcap) { keysF[p] = k3; idxF[p] = base + 3u; } }
  }
  if (blockIdx.x == 0 && (int)threadIdx.x < ntail) {
    int j = n4 * 4 + threadIdx.x;
    float x = in_s[j];
    uint32_t kk = f2key(x);
    uint32_t bb = kk >> 20;
    out_s[j] = (bb > sel) ? x : 0.0f;
    if (bb == sel) { uint32_t p = atomicAdd(&ws[CTRL + C_FBN], 1u); if (p < fbcap) { keysF[p] = kk; idxF[p] = (uint32_t)j; } }
  }
}

// Exact radix select + fixup. Happy: 32-bit select over compacted cands,
// zero losers. FB: 20-bit select within sel bin, restore winners.
__global__ void __launch_bounds__(1024) k_final(uint32_t* __restrict__ ws,
                                                const float* __restrict__ in,
                                                float* __restrict__ out,
                                                uint32_t n,
                                                const int* __restrict__ kptr,
                                                uint32_t fbcap) {
  __shared__ uint32_t sh[16384];
  __shared__ uint32_t red[16];
  __shared__ uint32_t s_p, s_want;
  int t = threadIdx.x;
  uint32_t fb = ws[CTRL + C_FLAG];
  int kv = kptr[0];
  uint32_t K = (kv < 1) ? 1u : (uint32_t)kv;
  if (K > n) K = n;
  uint32_t m, want, p0;
  int nbits;
  const uint32_t* keys;
  const uint32_t* idx;
  bool slow = false;
  if (!fb) {
    m = ws[CTRL + C_TOT]; want = K; p0 = 0u; nbits = 32;
    keys = ws + CMPK_OFF; idx = ws + CMPI_OFF;
  } else {
    m = ws[CTRL + C_FBN]; want = ws[CTRL + C_WANT]; p0 = ws[CTRL + C_SEL] << 20; nbits = 20;
    keys = ws + FBPK_OFF; idx = ws + FBPI_OFF;
    if (m > fbcap) { slow = true; m = n; }  // exact-but-slow input path
  }
  uint32_t selbin = p0 >> 20;
  bool useLds = (!slow && m <= 16384u);
  if (useLds) for (uint32_t i = t; i < m; i += 1024) sh[i] = keys[i];
  if (t == 0) { s_p = p0; s_want = want; }
  __syncthreads();
  uint32_t p = s_p;
  want = s_want;
  for (int bit = nbits - 1; bit >= 0; bit--) {
    uint32_t test = p | (1u << bit);
    uint32_t hi = test >> bit;
    uint32_t cnt = 0;
    for (uint32_t i = t; i < m; i += 1024) {
      uint32_t kk;
      if (slow) { kk = f2key(in[i]); if ((kk >> 20) != selbin) continue; }
      else kk = useLds ? sh[i] : keys[i];
      cnt += ((kk >> bit) == hi) ? 1u : 0u;
    }
    for (int off = 32; off; off >>= 1) cnt += __shfl_down((int)cnt, off);
    int wv = t >> 6, lane = t & 63;
    if (lane == 0) red[wv] = cnt;
    __syncthreads();
    if (t == 0) {
      uint32_t tot = 0;
      for (int w = 0; w < 16; w++) tot += red[w];
      if (tot >= want) p = test; else want -= tot;
      s_p = p; s_want = want;
    }
    __syncthreads();
    p = s_p; want = s_want;
  }
  if (t == 0) ws[CTRL + C_THR] = p;
  if (!fb) {        // zero the losers among candidates (winners already set)
    for (uint32_t i = t; i < m; i += 1024) {
      uint32_t kk = useLds ? sh[i] : keys[i];
      if (kk < p) out[idx[i]] = 0.0f;
    }
  } else if (!slow) {  // restore winners in sel bin
    for (uint32_t i = t; i < m; i += 1024) {
      uint32_t kk = useLds ? sh[i] : keys[i];
      if (kk >= p) out[idx[i]] = key2f(kk);
    }
  } else {
    for (uint32_t i = t; i < n; i += 1024) {
      uint32_t kk = f2key(in[i]);
      if ((kk >> 20) == selbin && kk >= p) out[i] = in[i];
    }
  }
}

extern "C" void kernel_launch(void* const* d_in, const int* in_sizes, int n_in,
                              void* d_out, int out_size, void* d_ws, size_t ws_size,
                              hipStream_t stream) {
  const float* in = (const float*)d_in[0];
  const int* kptr = (const int*)d_in[1];
  float* out = (float*)d_out;
  int n = in_sizes[0];
  int n4 = n >> 2;
  int ntail = n & 3;

  uint32_t* ws = (uint32_t*)d_ws;
  int64_t ws_words = (int64_t)(ws_size / 4);

  // capacity guards (degrade -> FB path, never OOB)
  int64_t fbw = (ws_words < (int64_t)CMPK_OFF ? ws_words : (int64_t)CMPK_OFF) - (int64_t)FBPK_OFF;
  uint32_t fbcap = fbw >= (int64_t)2 * FB_CAP ? FB_CAP : (fbw > 0 ? (uint32_t)(fbw / 2) : 0u);
  int64_t cmw = (ws_words < (int64_t)REG_OFF ? ws_words : (int64_t)REG_OFF) - (int64_t)CMPK_OFF;
  uint32_t cmpcap = cmw >= (int64_t)2 * CMP_CAP ? CMP_CAP : (cmw > 0 ? (uint32_t)(cmw / 2) : 0u);
  int64_t regw = ws_words - (int64_t)REG_OFF;
  uint32_t cap = regw > 0 ? (uint32_t)(regw / (2 * (int64_t)NW)) : 0u;
  if (cap > 64u) cap = 64u;
  uint32_t* keysR = ws + REG_OFF;
  uint32_t* idxR = keysR + (size_t)NW * cap;

  size_t zbytes = (size_t)ZERO_WORDS * 4;
  if (zbytes > ws_size) zbytes = ws_size;
  hipMemsetAsync(d_ws, 0, zbytes, stream);

  k_sample<<<256, 256, 0, stream>>>((const float4*)in, n4, kptr, (uint32_t)n, ws);
  k_apply_gather<<<1024, 256, 0, stream>>>((const float4*)in, (float4*)out,
                                           n4, ntail, in, out, ws, keysR, idxR, cap);
  k_compact<<<64, 256, 0, stream>>>(ws, keysR, idxR, cap, cmpcap, kptr, (uint32_t)n);
  k_fb_hist<<<1024, 256, 0, stream>>>((const float4*)in, n4, ntail, in, kptr,
                                      ws, (uint32_t)n);
  k_fb_ag<<<2048, 256, 0, stream>>>((const float4*)in, (float4*)out, n4, ntail,
                                    in, out, ws, fbcap);
  k_final<<<1, 1024, 0, stream>>>(ws, in, out, (uint32_t)n, kptr, fbcap);
}